// Round 1
// 706.818 us; speedup vs baseline: 1.3141x; 1.3141x over previous
//
#include <hip/hip_runtime.h>
#include <hip/hip_bf16.h>

// ---------------- degree (into int tmp array, NOT dinv) ----------------
__global__ __launch_bounds__(256) void k_deg(const int* __restrict__ dst, int* __restrict__ deg, int E) {
    int e = blockIdx.x * 256 + threadIdx.x;
    if (e < E) atomicAdd(&deg[dst[e]], 1);
}

// dinv[n] = rsqrt(deg[n] + 1)   (self-loop)
__global__ __launch_bounds__(256) void k_dinv(const int* __restrict__ deg, float* __restrict__ dinv, int N) {
    int n = blockIdx.x * 256 + threadIdx.x;
    if (n < N) dinv[n] = rsqrtf((float)(deg[n] + 1));
}

// ---------------- CSR build: 3-kernel exclusive scan + atomic-cursor fill ----------------
// k_scan_sum: bsum[b] = sum of deg[b*256 .. b*256+255]
__global__ __launch_bounds__(256) void k_scan_sum(const int* __restrict__ deg, int* __restrict__ bsum, int N) {
    int n = blockIdx.x * 256 + threadIdx.x;
    int v = (n < N) ? deg[n] : 0;
#pragma unroll
    for (int o = 32; o > 0; o >>= 1) v += __shfl_down(v, o, 64);
    __shared__ int sh[4];
    if ((threadIdx.x & 63) == 0) sh[threadIdx.x >> 6] = v;
    __syncthreads();
    if (threadIdx.x == 0) bsum[blockIdx.x] = sh[0] + sh[1] + sh[2] + sh[3];
}

// k_scan_off: in-place exclusive scan of bsum[0..nb), nb <= 256 (N=50000 -> nb=196)
__global__ __launch_bounds__(256) void k_scan_off(int* __restrict__ bsum, int nb) {
    __shared__ int sh[256];
    int t = threadIdx.x;
    sh[t] = (t < nb) ? bsum[t] : 0;
    __syncthreads();
    for (int o = 1; o < 256; o <<= 1) {
        int y = (t >= o) ? sh[t - o] : 0;
        __syncthreads();
        sh[t] += y;
        __syncthreads();
    }
    if (t < nb) bsum[t] = (t == 0) ? 0 : sh[t - 1];
}

// k_scan_write: row_start[n] = boff[blk] + exclusive_scan_in_block(deg); cursor = copy; row_start[N] = E
__global__ __launch_bounds__(256) void k_scan_write(const int* __restrict__ deg, const int* __restrict__ boff,
                                                    int* __restrict__ row_start, int* __restrict__ cursor, int N) {
    int n = blockIdx.x * 256 + threadIdx.x;
    int t = threadIdx.x, lane = t & 63, w = t >> 6;
    int v = (n < N) ? deg[n] : 0;
    int x = v;
#pragma unroll
    for (int o = 1; o < 64; o <<= 1) {
        int y = __shfl_up(x, o, 64);
        if (lane >= o) x += y;
    }
    __shared__ int wsum[4];
    if (lane == 63) wsum[w] = x;
    __syncthreads();
    int wo = 0;
#pragma unroll
    for (int i = 0; i < 4; ++i) wo += (i < w) ? wsum[i] : 0;
    int excl = boff[blockIdx.x] + wo + x - v;
    if (n < N) { row_start[n] = excl; cursor[n] = excl; }
    if (n == N - 1) row_start[N] = excl + v;
}

// k_fill: col[atomic slot within dst bucket] = src
__global__ __launch_bounds__(256) void k_fill(const int* __restrict__ src, const int* __restrict__ dst,
                                              int* __restrict__ cursor, int* __restrict__ col, int E) {
    int e = blockIdx.x * 256 + threadIdx.x;
    if (e < E) {
        int d = dst[e];
        int pos = atomicAdd(&cursor[d], 1);
        col[pos] = src[e];
    }
}

// ---------------- tiny transpose: out[c][r] = in[r][c], in is [R][C] row-major ----------------
__global__ __launch_bounds__(256) void k_tr(const float* __restrict__ in, float* __restrict__ outp, int R, int C) {
    int i = blockIdx.x * 256 + threadIdx.x;
    if (i < R * C) {
        int r = i / C, c = i % C;
        outp[(size_t)c * R + r] = in[(size_t)r * C + c];
    }
}

// WPQ[j][k] j in [0,128), k in [0,64):  j<64 -> Wa^T (Wm1[k][j]), else Wb^T (Wm1[64+k][j-64])
__global__ __launch_bounds__(256) void k_wpq(const float* __restrict__ Wm1, float* __restrict__ WPQ) {
    int i = blockIdx.x * 256 + threadIdx.x;
    if (i < 128 * 64) {
        int j = i >> 6, k = i & 63;
        WPQ[i] = (j < 64) ? Wm1[k * 64 + j] : Wm1[(64 + k) * 64 + (j - 64)];
    }
}

// ---------------- register-blocked node GEMM + fused agg-init (HW-proven) ----------------
// thread = node n. acc[64] in VGPRs; weights via uniform s_load from WT [64][K].
// Writes H[n] = act(X[n]) @ W   and   A[n] = bias + H[n]*dinv[n]^2  (self-loop term).
// A may alias X (each thread reads only its own row before writing it).
template <int K, bool RELU>
__global__ __launch_bounds__(256) void k_mm_reg(const float* __restrict__ X,
                                                const float* __restrict__ WT,
                                                const float* __restrict__ bias,
                                                const float* __restrict__ dinv,
                                                float* __restrict__ H,
                                                float* __restrict__ A, int N) {
    int n = blockIdx.x * 256 + threadIdx.x;
    int nc = n < N ? n : N - 1;
    const float* xr = X + (size_t)nc * K;
    float acc[64];
#pragma unroll
    for (int j = 0; j < 64; ++j) acc[j] = 0.f;
#pragma unroll 1
    for (int k0 = 0; k0 < K; k0 += 8) {
        float ef[8];
        *(float4*)(ef)     = *(const float4*)(xr + k0);
        *(float4*)(ef + 4) = *(const float4*)(xr + k0 + 4);
        if (RELU) {
#pragma unroll
            for (int kk = 0; kk < 8; ++kk) ef[kk] = fmaxf(ef[kk], 0.f);
        }
#pragma unroll
        for (int j = 0; j < 64; ++j) {
#pragma unroll
            for (int kk = 0; kk < 8; ++kk)
                acc[j] = fmaf(ef[kk], WT[j * K + k0 + kk], acc[j]);
        }
    }
    if (n < N) {
        float dn = dinv[n];
        float dn2 = dn * dn;
        float hrow[64], arow[64];
#pragma unroll
        for (int j = 0; j < 64; ++j) {
            hrow[j] = acc[j];
            arow[j] = fmaf(acc[j], dn2, bias[j]);
        }
        float4* hp = (float4*)(H + (size_t)n * 64);
        float4* ap = (float4*)(A + (size_t)n * 64);
#pragma unroll
        for (int q = 0; q < 16; ++q) {
            hp[q] = *(float4*)(hrow + q * 4);
            ap[q] = *(float4*)(arow + q * 4);
        }
    }
}

// ---------------- CSR gather aggregation: a[d][lane] += sum_{e in in(d)} h[src_e][lane]*dinv[s]*dinv[d] ----------------
// wave = dst node, lane = column. Coalesced 256B row reads, ONE non-atomic row write per node.
__global__ __launch_bounds__(256) void k_gather(const float* __restrict__ h, const float* __restrict__ dinv,
                                                const int* __restrict__ row_start, const int* __restrict__ col,
                                                float* __restrict__ a, int N) {
    int w = threadIdx.x >> 6, lane = threadIdx.x & 63;
    int d = blockIdx.x * 4 + w;
    if (d >= N) return;
    int beg = row_start[d], end = row_start[d + 1];
    float dd = dinv[d];
    float acc = 0.f;
    int k = beg;
    for (; k + 4 <= end; k += 4) {
        int s0 = col[k], s1 = col[k + 1], s2 = col[k + 2], s3 = col[k + 3];
        float n0 = dinv[s0] * dd, n1 = dinv[s1] * dd;
        float n2 = dinv[s2] * dd, n3 = dinv[s3] * dd;
        float v0 = h[(size_t)s0 * 64 + lane], v1 = h[(size_t)s1 * 64 + lane];
        float v2 = h[(size_t)s2 * 64 + lane], v3 = h[(size_t)s3 * 64 + lane];
        acc = fmaf(v0, n0, acc);
        acc = fmaf(v1, n1, acc);
        acc = fmaf(v2, n2, acc);
        acc = fmaf(v3, n3, acc);
    }
    for (; k < end; ++k) {
        int s = col[k];
        acc = fmaf(h[(size_t)s * 64 + lane], dinv[s] * dd, acc);
    }
    a[(size_t)d * 64 + lane] += acc;
}

// ---------------- P/Q node pass: z = relu(A2[n]);  Q[n] = z@Wb ; P[n] = z@Wa + bm1 (in-place over A2) ----------------
__global__ __launch_bounds__(256) void k_pq(float* __restrict__ A2P,
                                            const float* __restrict__ WPQ,  // [128][64]
                                            const float* __restrict__ bm1,
                                            float* __restrict__ Qb, int N) {
    int n = blockIdx.x * 256 + threadIdx.x;
    int nc = n < N ? n : N - 1;
    const float* xr = A2P + (size_t)nc * 64;
    // ---- Q = relu(row) @ Wb ----
    {
        float acc[64];
#pragma unroll
        for (int j = 0; j < 64; ++j) acc[j] = 0.f;
#pragma unroll 1
        for (int k0 = 0; k0 < 64; k0 += 8) {
            float ef[8];
            *(float4*)(ef)     = *(const float4*)(xr + k0);
            *(float4*)(ef + 4) = *(const float4*)(xr + k0 + 4);
#pragma unroll
            for (int kk = 0; kk < 8; ++kk) ef[kk] = fmaxf(ef[kk], 0.f);
#pragma unroll
            for (int j = 0; j < 64; ++j)
#pragma unroll
                for (int kk = 0; kk < 8; ++kk)
                    acc[j] = fmaf(ef[kk], WPQ[(64 + j) * 64 + k0 + kk], acc[j]);
        }
        if (n < N) {
#pragma unroll
            for (int q = 0; q < 16; ++q)
                *(float4*)(Qb + (size_t)n * 64 + q * 4) = *(float4*)(acc + q * 4);
        }
    }
    // ---- P = relu(row) @ Wa + bm1, overwrite row ----
    {
        float acc[64];
#pragma unroll
        for (int j = 0; j < 64; ++j) acc[j] = bm1[j];
#pragma unroll 1
        for (int k0 = 0; k0 < 64; k0 += 8) {
            float ef[8];
            *(float4*)(ef)     = *(const float4*)(xr + k0);
            *(float4*)(ef + 4) = *(const float4*)(xr + k0 + 4);
#pragma unroll
            for (int kk = 0; kk < 8; ++kk) ef[kk] = fmaxf(ef[kk], 0.f);
#pragma unroll
            for (int j = 0; j < 64; ++j)
#pragma unroll
                for (int kk = 0; kk < 8; ++kk)
                    acc[j] = fmaf(ef[kk], WPQ[j * 64 + k0 + kk], acc[j]);
        }
        if (n < N) {
#pragma unroll
            for (int q = 0; q < 16; ++q)
                *(float4*)(A2P + (size_t)n * 64 + q * 4) = *(float4*)(acc + q * 4);
        }
    }
}

// ---------------- edge epilogue: out[e] = relu(P[s] + Q[d]) @ Wm2 + bm2 ----------------
__global__ __launch_bounds__(256) void k_edge_pq(const float* __restrict__ P,
                                                 const float* __restrict__ Q,
                                                 const int* __restrict__ src,
                                                 const int* __restrict__ dst,
                                                 const float* __restrict__ W2T,  // [16][64]
                                                 const float* __restrict__ bm2,
                                                 float* __restrict__ out, int E) {
    int e = blockIdx.x * 256 + threadIdx.x;
    int ec = e < E ? e : E - 1;
    int s = src[ec], d = dst[ec];
    const float4* p4 = (const float4*)(P + (size_t)s * 64);
    const float4* q4 = (const float4*)(Q + (size_t)d * 64);
    float z[64];
#pragma unroll
    for (int c = 0; c < 16; ++c) {
        float4 a = p4[c], b = q4[c];
        z[c * 4 + 0] = fmaxf(a.x + b.x, 0.f);
        z[c * 4 + 1] = fmaxf(a.y + b.y, 0.f);
        z[c * 4 + 2] = fmaxf(a.z + b.z, 0.f);
        z[c * 4 + 3] = fmaxf(a.w + b.w, 0.f);
    }
    float o[16];
#pragma unroll
    for (int c = 0; c < 16; ++c) {
        float a = bm2[c];
#pragma unroll
        for (int j = 0; j < 64; ++j) a = fmaf(z[j], W2T[c * 64 + j], a);
        o[c] = a;
    }
    if (e < E) {
        float4* op = (float4*)(out + (size_t)e * 16);
#pragma unroll
        for (int q = 0; q < 4; ++q) op[q] = *(float4*)(o + q * 4);
    }
}

extern "C" void kernel_launch(void* const* d_in, const int* in_sizes, int n_in,
                              void* d_out, int out_size, void* d_ws, size_t ws_size,
                              hipStream_t stream) {
    const float* x   = (const float*)d_in[0];
    const int* ei    = (const int*)d_in[1];
    const float* W1  = (const float*)d_in[2];
    const float* b1  = (const float*)d_in[3];
    const float* W2  = (const float*)d_in[4];
    const float* b2  = (const float*)d_in[5];
    const float* Wm1 = (const float*)d_in[6];
    const float* bm1 = (const float*)d_in[7];
    const float* Wm2 = (const float*)d_in[8];
    const float* bm2 = (const float*)d_in[9];
    float* out = (float*)d_out;

    const int H  = in_sizes[3];          // 64
    const int IN = in_sizes[2] / H;      // 128
    const int N  = in_sizes[0] / IN;     // 50000
    const int E  = in_sizes[1] / 2;      // 800000
    const int* src = ei;
    const int* dst = ei + E;

    // ws: dinv + weights + bufB(12.8MB) + Qbuf(12.8MB) = 25.89 MB (fits; proven previously).
    // bufA (h) lives in d_out (dead before k_edge_pq writes the real output).
    // CSR arrays (deg/row_start/cursor/bsum/col ~3.8 MB) alias Qbuf: Qbuf is only
    // written by k_pq, which runs AFTER the last k_gather consumes the CSR.
    char* ws = (char*)d_ws;
    size_t off = 0;
    auto alloc = [&](size_t bytes) { void* p = ws + off; off += (bytes + 255) & ~(size_t)255; return p; };
    float* dinv = (float*)alloc((size_t)N * 4);
    float* W1T  = (float*)alloc((size_t)IN * H * 4);     // [64][128]
    float* W2T  = (float*)alloc((size_t)H * H * 4);      // [64][64]
    float* WPQ  = (float*)alloc((size_t)2 * H * H * 4);  // [128][64]
    float* Wm2T = (float*)alloc((size_t)H * 16 * 4);     // [16][64]
    float* bufB = (float*)alloc((size_t)N * 64 * 4);
    float* Qbuf = (float*)alloc((size_t)N * 64 * 4);
    float* bufA = (float*)d_out;
    float* Pbuf = bufB;

    // CSR layout inside Qbuf (all int32)
    const int Npad = (N + 255) & ~255;       // 50176 for N=50000
    int* degtmp = (int*)Qbuf;
    int* rowst  = degtmp + Npad;             // N+1 entries
    int* cursor = rowst + Npad;              // N entries
    int* bsum   = cursor + Npad;             // <=256 entries
    int* col    = bsum + 256;                // E entries

    const int NBn = (N + 255) / 256;         // 196 blocks (<=256 required by k_scan_off)
    const int NBe = (E + 255) / 256;

    // ---- degree + dinv + CSR build (once; shared by both layers) ----
    hipMemsetAsync(degtmp, 0, (size_t)N * sizeof(int), stream);
    k_deg<<<NBe, 256, 0, stream>>>(dst, degtmp, E);
    k_dinv<<<NBn, 256, 0, stream>>>(degtmp, dinv, N);
    k_scan_sum<<<NBn, 256, 0, stream>>>(degtmp, bsum, N);
    k_scan_off<<<1, 256, 0, stream>>>(bsum, NBn);
    k_scan_write<<<NBn, 256, 0, stream>>>(degtmp, bsum, rowst, cursor, N);
    k_fill<<<NBe, 256, 0, stream>>>(src, dst, cursor, col, E);

    // ---- weight transposes ----
    k_tr<<<(IN * H + 255) / 256, 256, 0, stream>>>(W1, W1T, IN, H);
    k_tr<<<(H * H + 255) / 256, 256, 0, stream>>>(W2, W2T, H, H);
    k_tr<<<(H * 16 + 255) / 256, 256, 0, stream>>>(Wm2, Wm2T, H, 16);
    k_wpq<<<(2 * H * H + 255) / 256, 256, 0, stream>>>(Wm1, WPQ);

    const int NB = (N + 255) / 256;          // thread = node
    const int NG = (N + 3) / 4;              // wave = node

    // layer 1: h1 = x@W1 -> bufA ; a1 = b1 + h1*dinv^2 -> bufB ; + CSR gather
    k_mm_reg<128, false><<<NB, 256, 0, stream>>>(x, W1T, b1, dinv, bufA, bufB, N);
    k_gather<<<NG, 256, 0, stream>>>(bufA, dinv, rowst, col, bufB, N);

    // layer 2: h2 = relu(a1)@W2 -> bufA ; a2 = b2 + h2*dinv^2 -> bufB (in-place, row-local) ; + gather
    k_mm_reg<64, true><<<NB, 256, 0, stream>>>(bufB, W2T, b2, dinv, bufA, bufB, N);
    k_gather<<<NG, 256, 0, stream>>>(bufA, dinv, rowst, col, bufB, N);

    // node-side MLP halves: Q = relu(a2)@Wb -> Qbuf ; P = relu(a2)@Wa + bm1 -> in-place over a2
    k_pq<<<NB, 256, 0, stream>>>(bufB, WPQ, bm1, Qbuf, N);

    // edge epilogue
    k_edge_pq<<<NBe, 256, 0, stream>>>(Pbuf, Qbuf, src, dst, Wm2T, bm2, out, E);
}

// Round 2
// 451.088 us; speedup vs baseline: 2.0591x; 1.5669x over previous
//
#include <hip/hip_runtime.h>
#include <hip/hip_bf16.h>

// ---------------- degree (into int tmp array) ----------------
__global__ __launch_bounds__(256) void k_deg(const int* __restrict__ dst, int* __restrict__ deg, int E) {
    int e = blockIdx.x * 256 + threadIdx.x;
    if (e < E) atomicAdd(&deg[dst[e]], 1);
}

// dinv[n] = rsqrt(deg[n] + 1)   (self-loop)
__global__ __launch_bounds__(256) void k_dinv(const int* __restrict__ deg, float* __restrict__ dinv, int N) {
    int n = blockIdx.x * 256 + threadIdx.x;
    if (n < N) dinv[n] = rsqrtf((float)(deg[n] + 1));
}

// ---------------- CSR build: 3-kernel exclusive scan + atomic-cursor fill ----------------
__global__ __launch_bounds__(256) void k_scan_sum(const int* __restrict__ deg, int* __restrict__ bsum, int N) {
    int n = blockIdx.x * 256 + threadIdx.x;
    int v = (n < N) ? deg[n] : 0;
#pragma unroll
    for (int o = 32; o > 0; o >>= 1) v += __shfl_down(v, o, 64);
    __shared__ int sh[4];
    if ((threadIdx.x & 63) == 0) sh[threadIdx.x >> 6] = v;
    __syncthreads();
    if (threadIdx.x == 0) bsum[blockIdx.x] = sh[0] + sh[1] + sh[2] + sh[3];
}

__global__ __launch_bounds__(256) void k_scan_off(int* __restrict__ bsum, int nb) {
    __shared__ int sh[256];
    int t = threadIdx.x;
    sh[t] = (t < nb) ? bsum[t] : 0;
    __syncthreads();
    for (int o = 1; o < 256; o <<= 1) {
        int y = (t >= o) ? sh[t - o] : 0;
        __syncthreads();
        sh[t] += y;
        __syncthreads();
    }
    if (t < nb) bsum[t] = (t == 0) ? 0 : sh[t - 1];
}

__global__ __launch_bounds__(256) void k_scan_write(const int* __restrict__ deg, const int* __restrict__ boff,
                                                    int* __restrict__ row_start, int* __restrict__ cursor, int N) {
    int n = blockIdx.x * 256 + threadIdx.x;
    int t = threadIdx.x, lane = t & 63, w = t >> 6;
    int v = (n < N) ? deg[n] : 0;
    int x = v;
#pragma unroll
    for (int o = 1; o < 64; o <<= 1) {
        int y = __shfl_up(x, o, 64);
        if (lane >= o) x += y;
    }
    __shared__ int wsum[4];
    if (lane == 63) wsum[w] = x;
    __syncthreads();
    int wo = 0;
#pragma unroll
    for (int i = 0; i < 4; ++i) wo += (i < w) ? wsum[i] : 0;
    int excl = boff[blockIdx.x] + wo + x - v;
    if (n < N) { row_start[n] = excl; cursor[n] = excl; }
    if (n == N - 1) row_start[N] = excl + v;
}

__global__ __launch_bounds__(256) void k_fill(const int* __restrict__ src, const int* __restrict__ dst,
                                              int* __restrict__ cursor, int* __restrict__ col, int E) {
    int e = blockIdx.x * 256 + threadIdx.x;
    if (e < E) {
        int d = dst[e];
        int pos = atomicAdd(&cursor[d], 1);
        col[pos] = src[e];
    }
}

// ---------------- tiny transpose: out[c][r] = in[r][c], in is [R][C] row-major ----------------
__global__ __launch_bounds__(256) void k_tr(const float* __restrict__ in, float* __restrict__ outp, int R, int C) {
    int i = blockIdx.x * 256 + threadIdx.x;
    if (i < R * C) {
        int r = i / C, c = i % C;
        outp[(size_t)c * R + r] = in[(size_t)r * C + c];
    }
}

// WPQ[j][k] j in [0,128), k in [0,64):  j<64 -> Wa^T (Wm1[k][j]), else Wb^T (Wm1[64+k][j-64])
__global__ __launch_bounds__(256) void k_wpq(const float* __restrict__ Wm1, float* __restrict__ WPQ) {
    int i = blockIdx.x * 256 + threadIdx.x;
    if (i < 128 * 64) {
        int j = i >> 6, k = i & 63;
        WPQ[i] = (j < 64) ? Wm1[k * 64 + j] : Wm1[(64 + k) * 64 + (j - 64)];
    }
}

// ---------------- column-sliced node GEMM: Y[n][j0:j0+16] = act(X[n]) @ WT[j0:j0+16] (+bias) ----------------
// thread = node n, blockIdx.y = 16-col slice. 4x the waves of the full-row version
// (784 -> 3136 waves per GEMM), acc[16] keeps VGPRs low -> occupancy up.
// Writes only its disjoint 64B slice of Y; X is never aliased by Y.
template <int K, bool RELU, bool BIAS>
__global__ __launch_bounds__(256) void k_mm_slice(const float* __restrict__ X,
                                                  const float* __restrict__ WT,   // [64][K]
                                                  const float* __restrict__ bias,
                                                  float* __restrict__ Y, int N) {
    int n = blockIdx.x * 256 + threadIdx.x;
    int j0 = blockIdx.y * 16;
    int nc = n < N ? n : N - 1;
    const float* xr = X + (size_t)nc * K;
    const float* wr = WT + (size_t)j0 * K;
    float acc[16];
#pragma unroll
    for (int j = 0; j < 16; ++j) acc[j] = BIAS ? bias[j0 + j] : 0.f;
#pragma unroll 1
    for (int k0 = 0; k0 < K; k0 += 8) {
        float ef[8];
        *(float4*)(ef)     = *(const float4*)(xr + k0);
        *(float4*)(ef + 4) = *(const float4*)(xr + k0 + 4);
        if (RELU) {
#pragma unroll
            for (int kk = 0; kk < 8; ++kk) ef[kk] = fmaxf(ef[kk], 0.f);
        }
#pragma unroll
        for (int j = 0; j < 16; ++j) {
#pragma unroll
            for (int kk = 0; kk < 8; ++kk)
                acc[j] = fmaf(ef[kk], wr[j * K + k0 + kk], acc[j]);
        }
    }
    if (n < N) {
        float4* yp = (float4*)(Y + (size_t)n * 64 + j0);
#pragma unroll
        for (int q = 0; q < 4; ++q) yp[q] = *(float4*)(acc + q * 4);
    }
}

// ---------------- CSR gather w/ fused self-loop+bias: a[d] = bias + h[d]*dd^2 + sum_e h[src_e]*ds*dd ----------------
// wave = dst node, lane = column. Row-local full-row write (no RMW, no aliasing hazard).
__global__ __launch_bounds__(256) void k_gather(const float* __restrict__ h, const float* __restrict__ dinv,
                                                const int* __restrict__ row_start, const int* __restrict__ col,
                                                const float* __restrict__ bias,
                                                float* __restrict__ a, int N) {
    int w = threadIdx.x >> 6, lane = threadIdx.x & 63;
    int d = blockIdx.x * 4 + w;
    if (d >= N) return;
    int beg = row_start[d], end = row_start[d + 1];
    float dd = dinv[d];
    float acc = fmaf(h[(size_t)d * 64 + lane], dd * dd, bias[lane]);  // bias + self-loop
    int k = beg;
    for (; k + 4 <= end; k += 4) {
        int s0 = col[k], s1 = col[k + 1], s2 = col[k + 2], s3 = col[k + 3];
        float n0 = dinv[s0] * dd, n1 = dinv[s1] * dd;
        float n2 = dinv[s2] * dd, n3 = dinv[s3] * dd;
        float v0 = h[(size_t)s0 * 64 + lane], v1 = h[(size_t)s1 * 64 + lane];
        float v2 = h[(size_t)s2 * 64 + lane], v3 = h[(size_t)s3 * 64 + lane];
        acc = fmaf(v0, n0, acc);
        acc = fmaf(v1, n1, acc);
        acc = fmaf(v2, n2, acc);
        acc = fmaf(v3, n3, acc);
    }
    for (; k < end; ++k) {
        int s = col[k];
        acc = fmaf(h[(size_t)s * 64 + lane], dinv[s] * dd, acc);
    }
    a[(size_t)d * 64 + lane] = acc;
}

// ---------------- fallback P pass (row-local, in-place over A2) for small ws ----------------
__global__ __launch_bounds__(256) void k_p_inplace(float* __restrict__ A2P,
                                                   const float* __restrict__ WPQ,  // [128][64], rows 0..63 = Wa^T
                                                   const float* __restrict__ bm1, int N) {
    int n = blockIdx.x * 256 + threadIdx.x;
    int nc = n < N ? n : N - 1;
    const float* xr = A2P + (size_t)nc * 64;
    float acc[64];
#pragma unroll
    for (int j = 0; j < 64; ++j) acc[j] = bm1[j];
#pragma unroll 1
    for (int k0 = 0; k0 < 64; k0 += 8) {
        float ef[8];
        *(float4*)(ef)     = *(const float4*)(xr + k0);
        *(float4*)(ef + 4) = *(const float4*)(xr + k0 + 4);
#pragma unroll
        for (int kk = 0; kk < 8; ++kk) ef[kk] = fmaxf(ef[kk], 0.f);
#pragma unroll
        for (int j = 0; j < 64; ++j)
#pragma unroll
            for (int kk = 0; kk < 8; ++kk)
                acc[j] = fmaf(ef[kk], WPQ[j * 64 + k0 + kk], acc[j]);
    }
    if (n < N) {
#pragma unroll
        for (int q = 0; q < 16; ++q)
            *(float4*)(A2P + (size_t)n * 64 + q * 4) = *(float4*)(acc + q * 4);
    }
}

// ---------------- edge epilogue: out[e] = relu(P[s] + Q[d]) @ Wm2 + bm2 ----------------
__global__ __launch_bounds__(256) void k_edge_pq(const float* __restrict__ P,
                                                 const float* __restrict__ Q,
                                                 const int* __restrict__ src,
                                                 const int* __restrict__ dst,
                                                 const float* __restrict__ W2T,  // [16][64]
                                                 const float* __restrict__ bm2,
                                                 float* __restrict__ out, int E) {
    int e = blockIdx.x * 256 + threadIdx.x;
    int ec = e < E ? e : E - 1;
    int s = src[ec], d = dst[ec];
    const float4* p4 = (const float4*)(P + (size_t)s * 64);
    const float4* q4 = (const float4*)(Q + (size_t)d * 64);
    float z[64];
#pragma unroll
    for (int c = 0; c < 16; ++c) {
        float4 a = p4[c], b = q4[c];
        z[c * 4 + 0] = fmaxf(a.x + b.x, 0.f);
        z[c * 4 + 1] = fmaxf(a.y + b.y, 0.f);
        z[c * 4 + 2] = fmaxf(a.z + b.z, 0.f);
        z[c * 4 + 3] = fmaxf(a.w + b.w, 0.f);
    }
    float o[16];
#pragma unroll
    for (int c = 0; c < 16; ++c) {
        float a = bm2[c];
#pragma unroll
        for (int j = 0; j < 64; ++j) a = fmaf(z[j], W2T[c * 64 + j], a);
        o[c] = a;
    }
    if (e < E) {
        float4* op = (float4*)(out + (size_t)e * 16);
#pragma unroll
        for (int q = 0; q < 4; ++q) op[q] = *(float4*)(o + q * 4);
    }
}

extern "C" void kernel_launch(void* const* d_in, const int* in_sizes, int n_in,
                              void* d_out, int out_size, void* d_ws, size_t ws_size,
                              hipStream_t stream) {
    const float* x   = (const float*)d_in[0];
    const int* ei    = (const int*)d_in[1];
    const float* W1  = (const float*)d_in[2];
    const float* b1  = (const float*)d_in[3];
    const float* W2  = (const float*)d_in[4];
    const float* b2  = (const float*)d_in[5];
    const float* Wm1 = (const float*)d_in[6];
    const float* bm1 = (const float*)d_in[7];
    const float* Wm2 = (const float*)d_in[8];
    const float* bm2 = (const float*)d_in[9];
    float* out = (float*)d_out;

    const int H  = in_sizes[3];          // 64
    const int IN = in_sizes[2] / H;      // 128
    const int N  = in_sizes[0] / IN;     // 50000
    const int E  = in_sizes[1] / 2;      // 800000
    const int* src = ei;
    const int* dst = ei + E;

    // ws layout: dinv + weights + bufB(12.8) + Qbuf(12.8) [+ Pbuf(12.8) if ws allows].
    // bufA (h) lives in d_out (dead before k_edge_pq writes the real output).
    // CSR arrays (~3.8 MB) alias Qbuf: Qbuf first written by the Q GEMM, which runs
    // AFTER the last k_gather consumed the CSR.
    char* ws = (char*)d_ws;
    size_t off = 0;
    auto alloc = [&](size_t bytes) { void* p = ws + off; off += (bytes + 255) & ~(size_t)255; return p; };
    float* dinv = (float*)alloc((size_t)N * 4);
    float* W1T  = (float*)alloc((size_t)IN * H * 4);     // [64][128]
    float* W2T  = (float*)alloc((size_t)H * H * 4);      // [64][64]
    float* WPQ  = (float*)alloc((size_t)2 * H * H * 4);  // [128][64]
    float* Wm2T = (float*)alloc((size_t)H * 16 * 4);     // [16][64]
    float* bufB = (float*)alloc((size_t)N * 64 * 4);
    float* Qbuf = (float*)alloc((size_t)N * 64 * 4);
    float* PbufSep = (float*)alloc((size_t)N * 64 * 4);  // may exceed ws -> fallback
    const bool fastP = (off <= ws_size);
    float* bufA = (float*)d_out;
    float* Pbuf = fastP ? PbufSep : bufB;

    // CSR layout inside Qbuf (all int32)
    const int Npad = (N + 255) & ~255;
    int* degtmp = (int*)Qbuf;
    int* rowst  = degtmp + Npad;
    int* cursor = rowst + Npad;
    int* bsum   = cursor + Npad;
    int* col    = bsum + 256;

    const int NBn = (N + 255) / 256;         // 196 (<=256 required by k_scan_off)
    const int NBe = (E + 255) / 256;
    const int NG  = (N + 3) / 4;             // wave = node

    // ---- degree + dinv + CSR build (once; shared by both layers) ----
    hipMemsetAsync(degtmp, 0, (size_t)N * sizeof(int), stream);
    k_deg<<<NBe, 256, 0, stream>>>(dst, degtmp, E);
    k_dinv<<<NBn, 256, 0, stream>>>(degtmp, dinv, N);
    k_scan_sum<<<NBn, 256, 0, stream>>>(degtmp, bsum, N);
    k_scan_off<<<1, 256, 0, stream>>>(bsum, NBn);
    k_scan_write<<<NBn, 256, 0, stream>>>(degtmp, bsum, rowst, cursor, N);
    k_fill<<<NBe, 256, 0, stream>>>(src, dst, cursor, col, E);

    // ---- weight transposes ----
    k_tr<<<(IN * H + 255) / 256, 256, 0, stream>>>(W1, W1T, IN, H);
    k_tr<<<(H * H + 255) / 256, 256, 0, stream>>>(W2, W2T, H, H);
    k_tr<<<(H * 16 + 255) / 256, 256, 0, stream>>>(Wm2, Wm2T, H, 16);
    k_wpq<<<(2 * H * H + 255) / 256, 256, 0, stream>>>(Wm1, WPQ);

    const dim3 G4(NBn, 4);

    // layer 1: h1 = x@W1 -> bufA ; a1 = b1 + h1*dinv^2 + gather -> bufB
    k_mm_slice<128, false, false><<<G4, 256, 0, stream>>>(x, W1T, nullptr, bufA, N);
    k_gather<<<NG, 256, 0, stream>>>(bufA, dinv, rowst, col, b1, bufB, N);

    // layer 2: h2 = relu(a1)@W2 -> bufA ; a2 = b2 + h2*dinv^2 + gather -> bufB (bufB dead at gather time)
    k_mm_slice<64, true, false><<<G4, 256, 0, stream>>>(bufB, W2T, nullptr, bufA, N);
    k_gather<<<NG, 256, 0, stream>>>(bufA, dinv, rowst, col, b2, bufB, N);

    // node-side MLP halves: Q = relu(a2)@Wb -> Qbuf ; P = relu(a2)@Wa + bm1
    k_mm_slice<64, true, false><<<G4, 256, 0, stream>>>(bufB, WPQ + 64 * 64, nullptr, Qbuf, N);
    if (fastP) {
        k_mm_slice<64, true, true><<<G4, 256, 0, stream>>>(bufB, WPQ, bm1, PbufSep, N);
    } else {
        k_p_inplace<<<NBn, 256, 0, stream>>>(bufB, WPQ, bm1, N);
    }

    // edge epilogue
    k_edge_pq<<<NBe, 256, 0, stream>>>(Pbuf, Qbuf, src, dst, Wm2T, bm2, out, E);
}

// Round 3
// 431.592 us; speedup vs baseline: 2.1521x; 1.0452x over previous
//
#include <hip/hip_runtime.h>
#include <hip/hip_bf16.h>

// ---------------- degree ----------------
__global__ __launch_bounds__(256) void k_deg(const int* __restrict__ dst, int* __restrict__ deg, int E) {
    int e = blockIdx.x * 256 + threadIdx.x;
    if (e < E) atomicAdd(&deg[dst[e]], 1);
}

// dinv[n] = rsqrt(deg[n] + 1)   (self-loop)
__global__ __launch_bounds__(256) void k_dinv(const int* __restrict__ deg, float* __restrict__ dinv, int N) {
    int n = blockIdx.x * 256 + threadIdx.x;
    if (n < N) dinv[n] = rsqrtf((float)(deg[n] + 1));
}

// ---------------- CSR build: 3-kernel exclusive scan + atomic-cursor fill ----------------
__global__ __launch_bounds__(256) void k_scan_sum(const int* __restrict__ deg, int* __restrict__ bsum, int N) {
    int n = blockIdx.x * 256 + threadIdx.x;
    int v = (n < N) ? deg[n] : 0;
#pragma unroll
    for (int o = 32; o > 0; o >>= 1) v += __shfl_down(v, o, 64);
    __shared__ int sh[4];
    if ((threadIdx.x & 63) == 0) sh[threadIdx.x >> 6] = v;
    __syncthreads();
    if (threadIdx.x == 0) bsum[blockIdx.x] = sh[0] + sh[1] + sh[2] + sh[3];
}

__global__ __launch_bounds__(256) void k_scan_off(int* __restrict__ bsum, int nb) {
    __shared__ int sh[256];
    int t = threadIdx.x;
    sh[t] = (t < nb) ? bsum[t] : 0;
    __syncthreads();
    for (int o = 1; o < 256; o <<= 1) {
        int y = (t >= o) ? sh[t - o] : 0;
        __syncthreads();
        sh[t] += y;
        __syncthreads();
    }
    if (t < nb) bsum[t] = (t == 0) ? 0 : sh[t - 1];
}

__global__ __launch_bounds__(256) void k_scan_write(const int* __restrict__ deg, const int* __restrict__ boff,
                                                    int* __restrict__ row_start, int* __restrict__ cursor, int N) {
    int n = blockIdx.x * 256 + threadIdx.x;
    int t = threadIdx.x, lane = t & 63, w = t >> 6;
    int v = (n < N) ? deg[n] : 0;
    int x = v;
#pragma unroll
    for (int o = 1; o < 64; o <<= 1) {
        int y = __shfl_up(x, o, 64);
        if (lane >= o) x += y;
    }
    __shared__ int wsum[4];
    if (lane == 63) wsum[w] = x;
    __syncthreads();
    int wo = 0;
#pragma unroll
    for (int i = 0; i < 4; ++i) wo += (i < w) ? wsum[i] : 0;
    int excl = boff[blockIdx.x] + wo + x - v;
    if (n < N) { row_start[n] = excl; cursor[n] = excl; }
    if (n == N - 1) row_start[N] = excl + v;
}

// PAIR: item[pos] = {src[e], e} (int2) ; else item[pos] = e (int)
template <bool PAIR>
__global__ __launch_bounds__(256) void k_fill(const int* __restrict__ src, const int* __restrict__ dst,
                                              int* __restrict__ cursor, void* __restrict__ item, int E) {
    int e = blockIdx.x * 256 + threadIdx.x;
    if (e < E) {
        int d = dst[e];
        int pos = atomicAdd(&cursor[d], 1);
        if (PAIR) ((int2*)item)[pos] = make_int2(src[e], e);
        else      ((int*)item)[pos] = e;
    }
}

// ---------------- tiny transpose ----------------
__global__ __launch_bounds__(256) void k_tr(const float* __restrict__ in, float* __restrict__ outp, int R, int C) {
    int i = blockIdx.x * 256 + threadIdx.x;
    if (i < R * C) {
        int r = i / C, c = i % C;
        outp[(size_t)c * R + r] = in[(size_t)r * C + c];
    }
}

// WPQ[j][k]: j<64 -> Wa^T (Wm1[k][j]), else Wb^T (Wm1[64+k][j-64])
__global__ __launch_bounds__(256) void k_wpq(const float* __restrict__ Wm1, float* __restrict__ WPQ) {
    int i = blockIdx.x * 256 + threadIdx.x;
    if (i < 128 * 64) {
        int j = i >> 6, k = i & 63;
        WPQ[i] = (j < 64) ? Wm1[k * 64 + j] : Wm1[(64 + k) * 64 + (j - 64)];
    }
}

// ---------------- column-sliced node GEMM (HW-proven round 2) ----------------
template <int K, bool RELU, bool BIAS>
__global__ __launch_bounds__(256) void k_mm_slice(const float* __restrict__ X,
                                                  const float* __restrict__ WT,   // [64][K]
                                                  const float* __restrict__ bias,
                                                  float* __restrict__ Y, int N) {
    int n = blockIdx.x * 256 + threadIdx.x;
    int j0 = blockIdx.y * 16;
    int nc = n < N ? n : N - 1;
    const float* xr = X + (size_t)nc * K;
    const float* wr = WT + (size_t)j0 * K;
    float acc[16];
#pragma unroll
    for (int j = 0; j < 16; ++j) acc[j] = BIAS ? bias[j0 + j] : 0.f;
#pragma unroll 1
    for (int k0 = 0; k0 < K; k0 += 8) {
        float ef[8];
        *(float4*)(ef)     = *(const float4*)(xr + k0);
        *(float4*)(ef + 4) = *(const float4*)(xr + k0 + 4);
        if (RELU) {
#pragma unroll
            for (int kk = 0; kk < 8; ++kk) ef[kk] = fmaxf(ef[kk], 0.f);
        }
#pragma unroll
        for (int j = 0; j < 16; ++j) {
#pragma unroll
            for (int kk = 0; kk < 8; ++kk)
                acc[j] = fmaf(ef[kk], wr[j * K + k0 + kk], acc[j]);
        }
    }
    if (n < N) {
        float4* yp = (float4*)(Y + (size_t)n * 64 + j0);
#pragma unroll
        for (int q = 0; q < 4; ++q) yp[q] = *(float4*)(acc + q * 4);
    }
}

// ---------------- CSR gather w/ fused self-loop+bias ----------------
// wave = dst node, lane = column. PAIR: src from int2 item; else src = srcArr[eid].
template <bool PAIR>
__global__ __launch_bounds__(256) void k_gather(const float* __restrict__ h, const float* __restrict__ dinv,
                                                const int* __restrict__ row_start, const void* __restrict__ item,
                                                const int* __restrict__ srcArr,
                                                const float* __restrict__ bias,
                                                float* __restrict__ a, int N) {
    int w = threadIdx.x >> 6, lane = threadIdx.x & 63;
    int d = blockIdx.x * 4 + w;
    if (d >= N) return;
    int beg = row_start[d], end = row_start[d + 1];
    float dd = dinv[d];
    float acc = fmaf(h[(size_t)d * 64 + lane], dd * dd, bias[lane]);  // bias + self-loop
    int k = beg;
    for (; k + 4 <= end; k += 4) {
        int s0, s1, s2, s3;
        if (PAIR) {
            const int2* it = (const int2*)item;
            int2 p0 = it[k], p1 = it[k + 1], p2 = it[k + 2], p3 = it[k + 3];
            s0 = p0.x; s1 = p1.x; s2 = p2.x; s3 = p3.x;
        } else {
            const int* eid = (const int*)item;
            int e0 = eid[k], e1 = eid[k + 1], e2 = eid[k + 2], e3 = eid[k + 3];
            s0 = srcArr[e0]; s1 = srcArr[e1]; s2 = srcArr[e2]; s3 = srcArr[e3];
        }
        float n0 = dinv[s0] * dd, n1 = dinv[s1] * dd;
        float n2 = dinv[s2] * dd, n3 = dinv[s3] * dd;
        float v0 = h[(size_t)s0 * 64 + lane], v1 = h[(size_t)s1 * 64 + lane];
        float v2 = h[(size_t)s2 * 64 + lane], v3 = h[(size_t)s3 * 64 + lane];
        acc = fmaf(v0, n0, acc);
        acc = fmaf(v1, n1, acc);
        acc = fmaf(v2, n2, acc);
        acc = fmaf(v3, n3, acc);
    }
    for (; k < end; ++k) {
        int s;
        if (PAIR) s = ((const int2*)item)[k].x;
        else      s = srcArr[((const int*)item)[k]];
        acc = fmaf(h[(size_t)s * 64 + lane], dinv[s] * dd, acc);
    }
    a[(size_t)d * 64 + lane] = acc;
}

// ---------------- fallback P pass (row-local, in-place over A2) ----------------
__global__ __launch_bounds__(256) void k_p_inplace(float* __restrict__ A2P,
                                                   const float* __restrict__ WPQ,
                                                   const float* __restrict__ bm1, int N) {
    int n = blockIdx.x * 256 + threadIdx.x;
    int nc = n < N ? n : N - 1;
    const float* xr = A2P + (size_t)nc * 64;
    float acc[64];
#pragma unroll
    for (int j = 0; j < 64; ++j) acc[j] = bm1[j];
#pragma unroll 1
    for (int k0 = 0; k0 < 64; k0 += 8) {
        float ef[8];
        *(float4*)(ef)     = *(const float4*)(xr + k0);
        *(float4*)(ef + 4) = *(const float4*)(xr + k0 + 4);
#pragma unroll
        for (int kk = 0; kk < 8; ++kk) ef[kk] = fmaxf(ef[kk], 0.f);
#pragma unroll
        for (int j = 0; j < 64; ++j)
#pragma unroll
            for (int kk = 0; kk < 8; ++kk)
                acc[j] = fmaf(ef[kk], WPQ[j * 64 + k0 + kk], acc[j]);
    }
    if (n < N) {
#pragma unroll
        for (int q = 0; q < 16; ++q)
            *(float4*)(A2P + (size_t)n * 64 + q * 4) = *(float4*)(acc + q * 4);
    }
}

// ---------------- edge epilogue, ORIGINAL order (tier-C fallback) ----------------
__global__ __launch_bounds__(256) void k_edge_pq(const float* __restrict__ P,
                                                 const float* __restrict__ Q,
                                                 const int* __restrict__ src,
                                                 const int* __restrict__ dst,
                                                 const float* __restrict__ W2T,
                                                 const float* __restrict__ bm2,
                                                 float* __restrict__ out, int E) {
    int e = blockIdx.x * 256 + threadIdx.x;
    int ec = e < E ? e : E - 1;
    int s = src[ec], d = dst[ec];
    const float4* p4 = (const float4*)(P + (size_t)s * 64);
    const float4* q4 = (const float4*)(Q + (size_t)d * 64);
    float z[64];
#pragma unroll
    for (int c = 0; c < 16; ++c) {
        float4 a = p4[c], b = q4[c];
        z[c * 4 + 0] = fmaxf(a.x + b.x, 0.f);
        z[c * 4 + 1] = fmaxf(a.y + b.y, 0.f);
        z[c * 4 + 2] = fmaxf(a.z + b.z, 0.f);
        z[c * 4 + 3] = fmaxf(a.w + b.w, 0.f);
    }
    float o[16];
#pragma unroll
    for (int c = 0; c < 16; ++c) {
        float a = bm2[c];
#pragma unroll
        for (int j = 0; j < 64; ++j) a = fmaf(z[j], W2T[c * 64 + j], a);
        o[c] = a;
    }
    if (e < E) {
        float4* op = (float4*)(out + (size_t)e * 16);
#pragma unroll
        for (int q = 0; q < 4; ++q) op[q] = *(float4*)(o + q * 4);
    }
}

// ---------------- edge epilogue, CSR (dst-sorted) order ----------------
// thread = CSR position. Consecutive threads share d -> Q row read once per node (L1/L2 hit).
// d recovered by binary search on row_start (wave-mostly-uniform cached loads).
// out written scattered at out[eid]; each edge written exactly once.
template <bool PAIR>
__global__ __launch_bounds__(256) void k_edge_csr(const float* __restrict__ P,
                                                  const float* __restrict__ Q,
                                                  const int* __restrict__ rowst,
                                                  const void* __restrict__ item,
                                                  const int* __restrict__ srcArr,
                                                  const float* __restrict__ W2T,
                                                  const float* __restrict__ bm2,
                                                  float* __restrict__ out, int E, int N) {
    int i = blockIdx.x * 256 + threadIdx.x;
    int ic = i < E ? i : E - 1;
    int s, e;
    if (PAIR) {
        int2 pe = ((const int2*)item)[ic];
        s = pe.x; e = pe.y;
    } else {
        e = ((const int*)item)[ic];
        s = srcArr[e];
    }
    // largest d with rowst[d] <= ic  (rowst[0]=0, rowst[N]=E)
    int lo = 0, hi = N - 1;
    while (lo < hi) {
        int mid = (lo + hi + 1) >> 1;
        if (rowst[mid] <= ic) lo = mid; else hi = mid - 1;
    }
    const float4* p4 = (const float4*)(P + (size_t)s * 64);
    const float4* q4 = (const float4*)(Q + (size_t)lo * 64);
    float z[64];
#pragma unroll
    for (int c = 0; c < 16; ++c) {
        float4 a = p4[c], b = q4[c];
        z[c * 4 + 0] = fmaxf(a.x + b.x, 0.f);
        z[c * 4 + 1] = fmaxf(a.y + b.y, 0.f);
        z[c * 4 + 2] = fmaxf(a.z + b.z, 0.f);
        z[c * 4 + 3] = fmaxf(a.w + b.w, 0.f);
    }
    float o[16];
#pragma unroll
    for (int c = 0; c < 16; ++c) {
        float a = bm2[c];
#pragma unroll
        for (int j = 0; j < 64; ++j) a = fmaf(z[j], W2T[c * 64 + j], a);
        o[c] = a;
    }
    if (i < E) {
        float4* op = (float4*)(out + (size_t)e * 16);
#pragma unroll
        for (int q = 0; q < 4; ++q) op[q] = *(float4*)(o + q * 4);
    }
}

extern "C" void kernel_launch(void* const* d_in, const int* in_sizes, int n_in,
                              void* d_out, int out_size, void* d_ws, size_t ws_size,
                              hipStream_t stream) {
    const float* x   = (const float*)d_in[0];
    const int* ei    = (const int*)d_in[1];
    const float* W1  = (const float*)d_in[2];
    const float* b1  = (const float*)d_in[3];
    const float* W2  = (const float*)d_in[4];
    const float* b2  = (const float*)d_in[5];
    const float* Wm1 = (const float*)d_in[6];
    const float* bm1 = (const float*)d_in[7];
    const float* Wm2 = (const float*)d_in[8];
    const float* bm2 = (const float*)d_in[9];
    float* out = (float*)d_out;

    const int H  = in_sizes[3];          // 64
    const int IN = in_sizes[2] / H;      // 128
    const int N  = in_sizes[0] / IN;     // 50000
    const int E  = in_sizes[1] / 2;      // 800000
    const int* src = ei;
    const int* dst = ei + E;

    auto al = [](size_t b) { return (b + 255) & ~(size_t)255; };
    char* ws = (char*)d_ws;

    const size_t wb     = al((size_t)IN * H * 4) + al((size_t)H * H * 4) + al((size_t)2 * H * H * 4) + al((size_t)H * 16 * 4);
    const size_t rowstB = al(((size_t)N + 1) * 4);
    const size_t nodeB  = al((size_t)N * 64 * 4);
    const size_t pairB  = al((size_t)E * 8);
    const size_t eidB   = al((size_t)E * 4);
    const size_t needA  = wb + rowstB + pairB + 3 * nodeB;   // ~45.1 MB
    const size_t needB  = wb + rowstB + eidB  + 3 * nodeB;   // ~41.9 MB (fits 40 MiB ws)

    // tier 0: int2{src,eid} CSR epilogue; tier 1: eid-only (src via ei); tier 2: round-2 fallback
    const int tier = (needA <= ws_size) ? 0 : (needB <= ws_size) ? 1 : 2;

    float *W1T, *W2T, *WPQ, *Wm2T, *bufB, *Qbuf, *Pbuf, *dinv;
    int *deg, *rowst, *cursor, *bsum;
    void* item;
    float* bufA = (float*)d_out;   // h buffer: dead before the epilogue writes out
    bool slicedP = true;

    size_t off = 0;
    auto alc = [&](size_t b) { void* p = ws + off; off += al(b); return p; };

    if (tier <= 1) {
        W1T  = (float*)alc((size_t)IN * H * 4);
        W2T  = (float*)alc((size_t)H * H * 4);
        WPQ  = (float*)alc((size_t)2 * H * H * 4);
        Wm2T = (float*)alc((size_t)H * 16 * 4);
        rowst = (int*)alc(((size_t)N + 1) * 4);
        item  = alc(tier == 0 ? (size_t)E * 8 : (size_t)E * 4);
        bufB = (float*)alc((size_t)N * 64 * 4);
        Qbuf = (float*)alc((size_t)N * 64 * 4);
        Pbuf = (float*)alc((size_t)N * 64 * 4);
        // deg/dinv/cursor/bsum alias Pbuf: all dead before the P-GEMM writes Pbuf
        char* pz = (char*)Pbuf;
        dinv   = (float*)pz;
        deg    = (int*)(pz + al((size_t)N * 4));
        cursor = (int*)(pz + 2 * al((size_t)N * 4));
        bsum   = (int*)(pz + 3 * al((size_t)N * 4));
    } else {
        // round-2 proven layout: CSR lives in Qbuf (consumed before Q-GEMM writes it)
        dinv = (float*)alc((size_t)N * 4);
        W1T  = (float*)alc((size_t)IN * H * 4);
        W2T  = (float*)alc((size_t)H * H * 4);
        WPQ  = (float*)alc((size_t)2 * H * H * 4);
        Wm2T = (float*)alc((size_t)H * 16 * 4);
        bufB = (float*)alc((size_t)N * 64 * 4);
        Qbuf = (float*)alc((size_t)N * 64 * 4);
        float* PbufSep = (float*)alc((size_t)N * 64 * 4);
        slicedP = (off <= ws_size);
        Pbuf = slicedP ? PbufSep : bufB;
        char* qz = (char*)Qbuf;
        size_t qo = 0;
        deg    = (int*)(qz + qo); qo += al((size_t)N * 4);
        rowst  = (int*)(qz + qo); qo += al(((size_t)N + 1) * 4);
        cursor = (int*)(qz + qo); qo += al((size_t)N * 4);
        bsum   = (int*)(qz + qo); qo += al(1024);
        item   = (void*)(qz + qo);                      // int2 pairs, ~6.4 MB, fits in 12.8
    }

    const int NBn = (N + 255) / 256;   // 196 (<=256 required by k_scan_off)
    const int NBe = (E + 255) / 256;
    const int NG  = (N + 3) / 4;

    // ---- degree + dinv + CSR build ----
    hipMemsetAsync(deg, 0, (size_t)N * sizeof(int), stream);
    k_deg<<<NBe, 256, 0, stream>>>(dst, deg, E);
    k_dinv<<<NBn, 256, 0, stream>>>(deg, dinv, N);
    k_scan_sum<<<NBn, 256, 0, stream>>>(deg, bsum, N);
    k_scan_off<<<1, 256, 0, stream>>>(bsum, NBn);
    k_scan_write<<<NBn, 256, 0, stream>>>(deg, bsum, rowst, cursor, N);
    if (tier == 1) k_fill<false><<<NBe, 256, 0, stream>>>(src, dst, cursor, item, E);
    else           k_fill<true ><<<NBe, 256, 0, stream>>>(src, dst, cursor, item, E);

    // ---- weight transposes ----
    k_tr<<<(IN * H + 255) / 256, 256, 0, stream>>>(W1, W1T, IN, H);
    k_tr<<<(H * H + 255) / 256, 256, 0, stream>>>(W2, W2T, H, H);
    k_tr<<<(H * 16 + 255) / 256, 256, 0, stream>>>(Wm2, Wm2T, H, 16);
    k_wpq<<<(2 * H * H + 255) / 256, 256, 0, stream>>>(Wm1, WPQ);

    const dim3 G4(NBn, 4);

    // layer 1: h1 = x@W1 -> bufA ; a1 = b1 + self-loop + gather -> bufB
    k_mm_slice<128, false, false><<<G4, 256, 0, stream>>>(x, W1T, nullptr, bufA, N);
    if (tier == 1) k_gather<false><<<NG, 256, 0, stream>>>(bufA, dinv, rowst, item, src, b1, bufB, N);
    else           k_gather<true ><<<NG, 256, 0, stream>>>(bufA, dinv, rowst, item, src, b1, bufB, N);

    // layer 2
    k_mm_slice<64, true, false><<<G4, 256, 0, stream>>>(bufB, W2T, nullptr, bufA, N);
    if (tier == 1) k_gather<false><<<NG, 256, 0, stream>>>(bufA, dinv, rowst, item, src, b2, bufB, N);
    else           k_gather<true ><<<NG, 256, 0, stream>>>(bufA, dinv, rowst, item, src, b2, bufB, N);

    // node-side MLP halves: Q = relu(a2)@Wb -> Qbuf ; P = relu(a2)@Wa + bm1 -> Pbuf
    k_mm_slice<64, true, false><<<G4, 256, 0, stream>>>(bufB, WPQ + 64 * 64, nullptr, Qbuf, N);
    if (slicedP) k_mm_slice<64, true, true><<<G4, 256, 0, stream>>>(bufB, WPQ, bm1, Pbuf, N);
    else         k_p_inplace<<<NBn, 256, 0, stream>>>(bufB, WPQ, bm1, N);

    // edge epilogue
    if (tier == 0)      k_edge_csr<true ><<<NBe, 256, 0, stream>>>(Pbuf, Qbuf, rowst, item, src, Wm2T, bm2, out, E, N);
    else if (tier == 1) k_edge_csr<false><<<NBe, 256, 0, stream>>>(Pbuf, Qbuf, rowst, item, src, Wm2T, bm2, out, E, N);
    else                k_edge_pq<<<NBe, 256, 0, stream>>>(Pbuf, Qbuf, src, dst, Wm2T, bm2, out, E);
}

// Round 4
// 424.636 us; speedup vs baseline: 2.1874x; 1.0164x over previous
//
#include <hip/hip_runtime.h>
#include <hip/hip_bf16.h>

// ---------------- degree ----------------
__global__ __launch_bounds__(256) void k_deg(const int* __restrict__ dst, int* __restrict__ deg, int E) {
    int e = blockIdx.x * 256 + threadIdx.x;
    if (e < E) atomicAdd(&deg[dst[e]], 1);
}

// dinv[n] = rsqrt(deg[n] + 1)   (self-loop)
__global__ __launch_bounds__(256) void k_dinv(const int* __restrict__ deg, float* __restrict__ dinv, int N) {
    int n = blockIdx.x * 256 + threadIdx.x;
    if (n < N) dinv[n] = rsqrtf((float)(deg[n] + 1));
}

// ---------------- CSR build: 3-kernel exclusive scan + atomic-cursor fill ----------------
__global__ __launch_bounds__(256) void k_scan_sum(const int* __restrict__ deg, int* __restrict__ bsum, int N) {
    int n = blockIdx.x * 256 + threadIdx.x;
    int v = (n < N) ? deg[n] : 0;
#pragma unroll
    for (int o = 32; o > 0; o >>= 1) v += __shfl_down(v, o, 64);
    __shared__ int sh[4];
    if ((threadIdx.x & 63) == 0) sh[threadIdx.x >> 6] = v;
    __syncthreads();
    if (threadIdx.x == 0) bsum[blockIdx.x] = sh[0] + sh[1] + sh[2] + sh[3];
}

__global__ __launch_bounds__(256) void k_scan_off(int* __restrict__ bsum, int nb) {
    __shared__ int sh[256];
    int t = threadIdx.x;
    sh[t] = (t < nb) ? bsum[t] : 0;
    __syncthreads();
    for (int o = 1; o < 256; o <<= 1) {
        int y = (t >= o) ? sh[t - o] : 0;
        __syncthreads();
        sh[t] += y;
        __syncthreads();
    }
    if (t < nb) bsum[t] = (t == 0) ? 0 : sh[t - 1];
}

__global__ __launch_bounds__(256) void k_scan_write(const int* __restrict__ deg, const int* __restrict__ boff,
                                                    int* __restrict__ row_start, int* __restrict__ cursor, int N) {
    int n = blockIdx.x * 256 + threadIdx.x;
    int t = threadIdx.x, lane = t & 63, w = t >> 6;
    int v = (n < N) ? deg[n] : 0;
    int x = v;
#pragma unroll
    for (int o = 1; o < 64; o <<= 1) {
        int y = __shfl_up(x, o, 64);
        if (lane >= o) x += y;
    }
    __shared__ int wsum[4];
    if (lane == 63) wsum[w] = x;
    __syncthreads();
    int wo = 0;
#pragma unroll
    for (int i = 0; i < 4; ++i) wo += (i < w) ? wsum[i] : 0;
    int excl = boff[blockIdx.x] + wo + x - v;
    if (n < N) { row_start[n] = excl; cursor[n] = excl; }
    if (n == N - 1) row_start[N] = excl + v;
}

// PAIR: item[pos] = {src[e], e} (int2) ; else item[pos] = e (int)
template <bool PAIR>
__global__ __launch_bounds__(256) void k_fill(const int* __restrict__ src, const int* __restrict__ dst,
                                              int* __restrict__ cursor, void* __restrict__ item, int E) {
    int e = blockIdx.x * 256 + threadIdx.x;
    if (e < E) {
        int d = dst[e];
        int pos = atomicAdd(&cursor[d], 1);
        if (PAIR) ((int2*)item)[pos] = make_int2(src[e], e);
        else      ((int*)item)[pos] = e;
    }
}

// ---------------- dvec[i] = d for CSR position i (kills the epilogue binary search) ----------------
__global__ __launch_bounds__(256) void k_dvec(const int* __restrict__ rowst, int* __restrict__ dvec, int N) {
    int w = threadIdx.x >> 6, lane = threadIdx.x & 63;
    int d = blockIdx.x * 4 + w;
    if (d >= N) return;
    int beg = rowst[d], end = rowst[d + 1];
    for (int k = beg + lane; k < end; k += 64) dvec[k] = d;
}

// ---------------- tiny transpose ----------------
__global__ __launch_bounds__(256) void k_tr(const float* __restrict__ in, float* __restrict__ outp, int R, int C) {
    int i = blockIdx.x * 256 + threadIdx.x;
    if (i < R * C) {
        int r = i / C, c = i % C;
        outp[(size_t)c * R + r] = in[(size_t)r * C + c];
    }
}

// WPQ[j][k]: j<64 -> Wa^T (Wm1[k][j]), else Wb^T (Wm1[64+k][j-64])
__global__ __launch_bounds__(256) void k_wpq(const float* __restrict__ Wm1, float* __restrict__ WPQ) {
    int i = blockIdx.x * 256 + threadIdx.x;
    if (i < 128 * 64) {
        int j = i >> 6, k = i & 63;
        WPQ[i] = (j < 64) ? Wm1[k * 64 + j] : Wm1[(64 + k) * 64 + (j - 64)];
    }
}

// ---------------- column-sliced node GEMM (HW-proven round 2) ----------------
// SCALE: write acc*dinv[n]  ("hs" pre-scaled hidden rows -> gather needs no per-edge dinv[s])
template <int K, bool RELU, bool BIAS, bool SCALE>
__global__ __launch_bounds__(256) void k_mm_slice(const float* __restrict__ X,
                                                  const float* __restrict__ WT,   // [64][K]
                                                  const float* __restrict__ bias,
                                                  const float* __restrict__ dinv,
                                                  float* __restrict__ Y, int N) {
    int n = blockIdx.x * 256 + threadIdx.x;
    int j0 = blockIdx.y * 16;
    int nc = n < N ? n : N - 1;
    const float* xr = X + (size_t)nc * K;
    const float* wr = WT + (size_t)j0 * K;
    float acc[16];
#pragma unroll
    for (int j = 0; j < 16; ++j) acc[j] = BIAS ? bias[j0 + j] : 0.f;
#pragma unroll 1
    for (int k0 = 0; k0 < K; k0 += 8) {
        float ef[8];
        *(float4*)(ef)     = *(const float4*)(xr + k0);
        *(float4*)(ef + 4) = *(const float4*)(xr + k0 + 4);
        if (RELU) {
#pragma unroll
            for (int kk = 0; kk < 8; ++kk) ef[kk] = fmaxf(ef[kk], 0.f);
        }
#pragma unroll
        for (int j = 0; j < 16; ++j) {
#pragma unroll
            for (int kk = 0; kk < 8; ++kk)
                acc[j] = fmaf(ef[kk], wr[j * K + k0 + kk], acc[j]);
        }
    }
    if (n < N) {
        if (SCALE) {
            float dn = dinv[n];
#pragma unroll
            for (int j = 0; j < 16; ++j) acc[j] *= dn;
        }
        float4* yp = (float4*)(Y + (size_t)n * 64 + j0);
#pragma unroll
        for (int q = 0; q < 4; ++q) yp[q] = *(float4*)(acc + q * 4);
    }
}

// ---------------- fused P+Q GEMM: gridDim.y=8 over WPQ[128][64]; y<4 -> P(+bm1), y>=4 -> Q ----------------
__global__ __launch_bounds__(256) void k_pq_slice(const float* __restrict__ A2,
                                                  const float* __restrict__ WPQ,
                                                  const float* __restrict__ bm1,
                                                  float* __restrict__ Pb, float* __restrict__ Qb, int N) {
    int n = blockIdx.x * 256 + threadIdx.x;
    int j0g = blockIdx.y * 16;           // 0..127 row into WPQ
    bool isP = j0g < 64;
    int jo = isP ? j0g : j0g - 64;
    float* Y = isP ? Pb : Qb;
    int nc = n < N ? n : N - 1;
    const float* xr = A2 + (size_t)nc * 64;
    const float* wr = WPQ + (size_t)j0g * 64;
    float acc[16];
#pragma unroll
    for (int j = 0; j < 16; ++j) acc[j] = isP ? bm1[jo + j] : 0.f;
#pragma unroll 1
    for (int k0 = 0; k0 < 64; k0 += 8) {
        float ef[8];
        *(float4*)(ef)     = *(const float4*)(xr + k0);
        *(float4*)(ef + 4) = *(const float4*)(xr + k0 + 4);
#pragma unroll
        for (int kk = 0; kk < 8; ++kk) ef[kk] = fmaxf(ef[kk], 0.f);
#pragma unroll
        for (int j = 0; j < 16; ++j)
#pragma unroll
            for (int kk = 0; kk < 8; ++kk)
                acc[j] = fmaf(ef[kk], wr[j * 64 + k0 + kk], acc[j]);
    }
    if (n < N) {
        float4* yp = (float4*)(Y + (size_t)n * 64 + jo);
#pragma unroll
        for (int q = 0; q < 4; ++q) yp[q] = *(float4*)(acc + q * 4);
    }
}

// ---------------- CSR gather over pre-scaled rows: a[d] = bias + dd*(hs[d] + sum_e hs[src_e]) ----------------
// wave = dst node, lane = column. One row load + one add per edge; 8 rows in flight.
template <bool PAIR>
__global__ __launch_bounds__(256) void k_gather(const float* __restrict__ hs, const float* __restrict__ dinv,
                                                const int* __restrict__ row_start, const void* __restrict__ item,
                                                const int* __restrict__ srcArr,
                                                const float* __restrict__ bias,
                                                float* __restrict__ a, int N) {
    int w = threadIdx.x >> 6, lane = threadIdx.x & 63;
    int d = blockIdx.x * 4 + w;
    if (d >= N) return;
    int beg = row_start[d], end = row_start[d + 1];
    float dd = dinv[d];
    float acc = hs[(size_t)d * 64 + lane];   // self-loop term (pre-scaled)
    int k = beg;
    for (; k + 8 <= end; k += 8) {
        int ss[8];
        if (PAIR) {
            const int2* it = (const int2*)item;
#pragma unroll
            for (int u = 0; u < 8; ++u) ss[u] = it[k + u].x;
        } else {
            const int* eid = (const int*)item;
            int ee[8];
#pragma unroll
            for (int u = 0; u < 8; ++u) ee[u] = eid[k + u];
#pragma unroll
            for (int u = 0; u < 8; ++u) ss[u] = srcArr[ee[u]];
        }
        float v[8];
#pragma unroll
        for (int u = 0; u < 8; ++u) v[u] = hs[(size_t)ss[u] * 64 + lane];
#pragma unroll
        for (int u = 0; u < 8; ++u) acc += v[u];
    }
    for (; k < end; ++k) {
        int s = PAIR ? ((const int2*)item)[k].x : srcArr[((const int*)item)[k]];
        acc += hs[(size_t)s * 64 + lane];
    }
    a[(size_t)d * 64 + lane] = fmaf(acc, dd, bias[lane]);
}

// ---------------- fallback P pass (row-local, in-place over A2) ----------------
__global__ __launch_bounds__(256) void k_p_inplace(float* __restrict__ A2P,
                                                   const float* __restrict__ WPQ,
                                                   const float* __restrict__ bm1, int N) {
    int n = blockIdx.x * 256 + threadIdx.x;
    int nc = n < N ? n : N - 1;
    const float* xr = A2P + (size_t)nc * 64;
    float acc[64];
#pragma unroll
    for (int j = 0; j < 64; ++j) acc[j] = bm1[j];
#pragma unroll 1
    for (int k0 = 0; k0 < 64; k0 += 8) {
        float ef[8];
        *(float4*)(ef)     = *(const float4*)(xr + k0);
        *(float4*)(ef + 4) = *(const float4*)(xr + k0 + 4);
#pragma unroll
        for (int kk = 0; kk < 8; ++kk) ef[kk] = fmaxf(ef[kk], 0.f);
#pragma unroll
        for (int j = 0; j < 64; ++j)
#pragma unroll
            for (int kk = 0; kk < 8; ++kk)
                acc[j] = fmaf(ef[kk], WPQ[j * 64 + k0 + kk], acc[j]);
    }
    if (n < N) {
#pragma unroll
        for (int q = 0; q < 16; ++q)
            *(float4*)(A2P + (size_t)n * 64 + q * 4) = *(float4*)(acc + q * 4);
    }
}

// ---------------- edge epilogue, ORIGINAL order (tier-2 fallback) ----------------
__global__ __launch_bounds__(256) void k_edge_pq(const float* __restrict__ P,
                                                 const float* __restrict__ Q,
                                                 const int* __restrict__ src,
                                                 const int* __restrict__ dst,
                                                 const float* __restrict__ W2T,
                                                 const float* __restrict__ bm2,
                                                 float* __restrict__ out, int E) {
    int e = blockIdx.x * 256 + threadIdx.x;
    int ec = e < E ? e : E - 1;
    int s = src[ec], d = dst[ec];
    const float4* p4 = (const float4*)(P + (size_t)s * 64);
    const float4* q4 = (const float4*)(Q + (size_t)d * 64);
    float z[64];
#pragma unroll
    for (int c = 0; c < 16; ++c) {
        float4 a = p4[c], b = q4[c];
        z[c * 4 + 0] = fmaxf(a.x + b.x, 0.f);
        z[c * 4 + 1] = fmaxf(a.y + b.y, 0.f);
        z[c * 4 + 2] = fmaxf(a.z + b.z, 0.f);
        z[c * 4 + 3] = fmaxf(a.w + b.w, 0.f);
    }
    float o[16];
#pragma unroll
    for (int c = 0; c < 16; ++c) {
        float a = bm2[c];
#pragma unroll
        for (int j = 0; j < 64; ++j) a = fmaf(z[j], W2T[c * 64 + j], a);
        o[c] = a;
    }
    if (e < E) {
        float4* op = (float4*)(out + (size_t)e * 16);
#pragma unroll
        for (int q = 0; q < 4; ++q) op[q] = *(float4*)(o + q * 4);
    }
}

// ---------------- edge epilogue, CSR order, dvec-indexed (no binary search), fused accumulate ----------------
template <bool PAIR>
__global__ __launch_bounds__(256) void k_edge_csr(const float* __restrict__ P,
                                                  const float* __restrict__ Q,
                                                  const int* __restrict__ dvec,
                                                  const void* __restrict__ item,
                                                  const int* __restrict__ srcArr,
                                                  const float* __restrict__ W2T,  // [16][64]
                                                  const float* __restrict__ bm2,
                                                  float* __restrict__ out, int E) {
    int i = blockIdx.x * 256 + threadIdx.x;
    int ic = i < E ? i : E - 1;
    int s, e;
    if (PAIR) {
        int2 pe = ((const int2*)item)[ic];
        s = pe.x; e = pe.y;
    } else {
        e = ((const int*)item)[ic];
        s = srcArr[e];
    }
    int d = dvec[ic];
    const float4* p4 = (const float4*)(P + (size_t)s * 64);
    const float4* q4 = (const float4*)(Q + (size_t)d * 64);
    float o[16];
#pragma unroll
    for (int t = 0; t < 16; ++t) o[t] = bm2[t];
#pragma unroll
    for (int c = 0; c < 16; ++c) {
        float4 a = p4[c], b = q4[c];
        float z0 = fmaxf(a.x + b.x, 0.f);
        float z1 = fmaxf(a.y + b.y, 0.f);
        float z2 = fmaxf(a.z + b.z, 0.f);
        float z3 = fmaxf(a.w + b.w, 0.f);
#pragma unroll
        for (int t = 0; t < 16; ++t) {
            o[t] = fmaf(z0, W2T[t * 64 + c * 4 + 0], o[t]);
            o[t] = fmaf(z1, W2T[t * 64 + c * 4 + 1], o[t]);
            o[t] = fmaf(z2, W2T[t * 64 + c * 4 + 2], o[t]);
            o[t] = fmaf(z3, W2T[t * 64 + c * 4 + 3], o[t]);
        }
    }
    if (i < E) {
        float4* op = (float4*)(out + (size_t)e * 16);
#pragma unroll
        for (int q = 0; q < 4; ++q) op[q] = *(float4*)(o + q * 4);
    }
}

extern "C" void kernel_launch(void* const* d_in, const int* in_sizes, int n_in,
                              void* d_out, int out_size, void* d_ws, size_t ws_size,
                              hipStream_t stream) {
    const float* x   = (const float*)d_in[0];
    const int* ei    = (const int*)d_in[1];
    const float* W1  = (const float*)d_in[2];
    const float* b1  = (const float*)d_in[3];
    const float* W2  = (const float*)d_in[4];
    const float* b2  = (const float*)d_in[5];
    const float* Wm1 = (const float*)d_in[6];
    const float* bm1 = (const float*)d_in[7];
    const float* Wm2 = (const float*)d_in[8];
    const float* bm2 = (const float*)d_in[9];
    float* out = (float*)d_out;

    const int H  = in_sizes[3];          // 64
    const int IN = in_sizes[2] / H;      // 128
    const int N  = in_sizes[0] / IN;     // 50000
    const int E  = in_sizes[1] / 2;      // 800000
    const int* src = ei;
    const int* dst = ei + E;

    auto al = [](size_t b) { return (b + 255) & ~(size_t)255; };
    char* ws = (char*)d_ws;

    const size_t wb     = al((size_t)IN * H * 4) + al((size_t)H * H * 4) + al((size_t)2 * H * H * 4) + al((size_t)H * 16 * 4);
    const size_t rowstB = al(((size_t)N + 1) * 4);
    const size_t nodeB  = al((size_t)N * 64 * 4);
    const size_t pairB  = al((size_t)E * 8);
    const size_t eidB   = al((size_t)E * 4);
    const size_t needA  = wb + rowstB + pairB + 3 * nodeB;   // ~45.1 MB
    const size_t needB  = wb + rowstB + eidB  + 3 * nodeB;   // ~41.9 MB

    // tier 0: int2{src,eid} CSR epilogue; tier 1: eid-only (src via ei); tier 2: round-2 fallback
    const int tier = (needA <= ws_size) ? 0 : (needB <= ws_size) ? 1 : 2;

    float *W1T, *W2T, *WPQ, *Wm2T, *bufB, *Qbuf, *Pbuf, *dinv;
    int *deg, *rowst, *cursor, *bsum;
    void* item;
    float* bufA = (float*)d_out;   // hs buffer: dead before the epilogue writes out
    bool slicedP = true;

    size_t off = 0;
    auto alc = [&](size_t b) { void* p = ws + off; off += al(b); return p; };

    if (tier <= 1) {
        W1T  = (float*)alc((size_t)IN * H * 4);
        W2T  = (float*)alc((size_t)H * H * 4);
        WPQ  = (float*)alc((size_t)2 * H * H * 4);
        Wm2T = (float*)alc((size_t)H * 16 * 4);
        rowst = (int*)alc(((size_t)N + 1) * 4);
        item  = alc(tier == 0 ? (size_t)E * 8 : (size_t)E * 4);
        bufB = (float*)alc((size_t)N * 64 * 4);
        Qbuf = (float*)alc((size_t)N * 64 * 4);
        Pbuf = (float*)alc((size_t)N * 64 * 4);
        // deg/dinv/cursor/bsum alias Pbuf: all dead before the P-GEMM writes Pbuf
        // (dinv last used by gather2, which precedes k_pq_slice)
        char* pz = (char*)Pbuf;
        dinv   = (float*)pz;
        deg    = (int*)(pz + al((size_t)N * 4));
        cursor = (int*)(pz + 2 * al((size_t)N * 4));
        bsum   = (int*)(pz + 3 * al((size_t)N * 4));
    } else {
        // round-2 proven layout: CSR lives in Qbuf (consumed before Q-GEMM writes it)
        dinv = (float*)alc((size_t)N * 4);
        W1T  = (float*)alc((size_t)IN * H * 4);
        W2T  = (float*)alc((size_t)H * H * 4);
        WPQ  = (float*)alc((size_t)2 * H * H * 4);
        Wm2T = (float*)alc((size_t)H * 16 * 4);
        bufB = (float*)alc((size_t)N * 64 * 4);
        Qbuf = (float*)alc((size_t)N * 64 * 4);
        float* PbufSep = (float*)alc((size_t)N * 64 * 4);
        slicedP = (off <= ws_size);
        Pbuf = slicedP ? PbufSep : bufB;
        char* qz = (char*)Qbuf;
        size_t qo = 0;
        deg    = (int*)(qz + qo); qo += al((size_t)N * 4);
        rowst  = (int*)(qz + qo); qo += al(((size_t)N + 1) * 4);
        cursor = (int*)(qz + qo); qo += al((size_t)N * 4);
        bsum   = (int*)(qz + qo); qo += al(1024);
        item   = (void*)(qz + qo);                      // int2 pairs, ~6.4 MB, fits in 12.8
    }

    const int NBn = (N + 255) / 256;   // 196 (<=256 required by k_scan_off)
    const int NBe = (E + 255) / 256;
    const int NG  = (N + 3) / 4;

    // ---- degree + dinv + CSR build ----
    hipMemsetAsync(deg, 0, (size_t)N * sizeof(int), stream);
    k_deg<<<NBe, 256, 0, stream>>>(dst, deg, E);
    k_dinv<<<NBn, 256, 0, stream>>>(deg, dinv, N);
    k_scan_sum<<<NBn, 256, 0, stream>>>(deg, bsum, N);
    k_scan_off<<<1, 256, 0, stream>>>(bsum, NBn);
    k_scan_write<<<NBn, 256, 0, stream>>>(deg, bsum, rowst, cursor, N);
    if (tier == 1) k_fill<false><<<NBe, 256, 0, stream>>>(src, dst, cursor, item, E);
    else           k_fill<true ><<<NBe, 256, 0, stream>>>(src, dst, cursor, item, E);

    // ---- weight transposes ----
    k_tr<<<(IN * H + 255) / 256, 256, 0, stream>>>(W1, W1T, IN, H);
    k_tr<<<(H * H + 255) / 256, 256, 0, stream>>>(W2, W2T, H, H);
    k_tr<<<(H * 16 + 255) / 256, 256, 0, stream>>>(Wm2, Wm2T, H, 16);
    k_wpq<<<(2 * H * H + 255) / 256, 256, 0, stream>>>(Wm1, WPQ);

    const dim3 G4(NBn, 4);
    const dim3 G8(NBn, 8);

    // layer 1: hs1 = (x@W1)*dinv -> bufA ; a1 = b1 + dd*(hs1[d] + sum hs1[s]) -> bufB
    k_mm_slice<128, false, false, true><<<G4, 256, 0, stream>>>(x, W1T, nullptr, dinv, bufA, N);
    if (tier == 1) k_gather<false><<<NG, 256, 0, stream>>>(bufA, dinv, rowst, item, src, b1, bufB, N);
    else           k_gather<true ><<<NG, 256, 0, stream>>>(bufA, dinv, rowst, item, src, b1, bufB, N);

    // layer 2: hs2 = (relu(a1)@W2)*dinv -> bufA ; a2 -> bufB
    k_mm_slice<64, true, false, true><<<G4, 256, 0, stream>>>(bufB, W2T, nullptr, dinv, bufA, N);
    if (tier == 1) k_gather<false><<<NG, 256, 0, stream>>>(bufA, dinv, rowst, item, src, b2, bufB, N);
    else           k_gather<true ><<<NG, 256, 0, stream>>>(bufA, dinv, rowst, item, src, b2, bufB, N);

    // node-side MLP halves
    if (tier <= 1) {
        // fused P+Q in one dispatch (dinv dead from here; Pbuf write clobbers its alias region)
        k_pq_slice<<<G8, 256, 0, stream>>>(bufB, WPQ, bm1, Pbuf, Qbuf, N);
        // dvec into bufB (a2 dead after k_pq_slice)
        int* dvec = (int*)bufB;
        k_dvec<<<NG, 256, 0, stream>>>(rowst, dvec, N);
        if (tier == 0) k_edge_csr<true ><<<NBe, 256, 0, stream>>>(Pbuf, Qbuf, dvec, item, src, Wm2T, bm2, out, E);
        else           k_edge_csr<false><<<NBe, 256, 0, stream>>>(Pbuf, Qbuf, dvec, item, src, Wm2T, bm2, out, E);
    } else {
        k_mm_slice<64, true, false, false><<<G4, 256, 0, stream>>>(bufB, WPQ + 64 * 64, nullptr, nullptr, Qbuf, N);
        if (slicedP) k_mm_slice<64, true, true, false><<<G4, 256, 0, stream>>>(bufB, WPQ, bm1, nullptr, Pbuf, N);
        else         k_p_inplace<<<NBn, 256, 0, stream>>>(bufB, WPQ, bm1, N);
        k_edge_pq<<<NBe, 256, 0, stream>>>(Pbuf, Qbuf, src, dst, Wm2T, bm2, out, E);
    }
}